// Round 6
// baseline (43090.540 us; speedup 1.0000x reference)
//
#include <hip/hip_runtime.h>
#include <hip/hip_bf16.h>

#define NB 16
#define NS 2048
#define NE 1024
#define NH 4
#define NDH 256

typedef __hip_bfloat16 bf16;
typedef __attribute__((ext_vector_type(8))) short short8;
typedef __attribute__((ext_vector_type(4))) short s16x4;
typedef __attribute__((ext_vector_type(4))) float f32x4;

__device__ __forceinline__ float b2f(short s) {
  union { unsigned int u; float f; } v;
  v.u = ((unsigned int)(unsigned short)s) << 16;
  return v.f;
}

__device__ __forceinline__ short f2b(float f) {
  bf16 h = (bf16)f;
  return *(short*)&h;
}

__device__ __forceinline__ short8 cvt8(f32x4 a, f32x4 b) {
  short8 r;
  r[0] = f2b(a[0]); r[1] = f2b(a[1]); r[2] = f2b(a[2]); r[3] = f2b(a[3]);
  r[4] = f2b(b[0]); r[5] = f2b(b[1]); r[6] = f2b(b[2]); r[7] = f2b(b[3]);
  return r;
}

// ---- GEMM1: qkv(bf16) = x(fp32) @ W(fp32)^T + b(fp32), converted to bf16 ----
// 128x128 tile, BK=64, 256 threads (4 waves 2x2), 16x16x32 bf16 MFMA.
#define GST 72
__global__ __launch_bounds__(256, 1) void gemm_bt_bias(
    const float* __restrict__ A, const float* __restrict__ W,
    const float* __restrict__ bias, bf16* __restrict__ C,
    int M, int N, int K)
{
  __shared__ __attribute__((aligned(16))) bf16 As[128 * GST];
  __shared__ __attribute__((aligned(16))) bf16 Bs[128 * GST];
  const int tid = threadIdx.x;
  const int wave = tid >> 6;
  const int lane = tid & 63;
  const int quad = lane >> 4;
  const int col = lane & 15;
  const int wm = wave & 1, wn = wave >> 1;
  const long mBase = (long)blockIdx.x * 128;
  const long nBase = (long)blockIdx.y * 128;

  f32x4 acc[4][4];
#pragma unroll
  for (int i = 0; i < 4; ++i)
#pragma unroll
    for (int j = 0; j < 4; ++j) acc[i][j] = (f32x4){0.f, 0.f, 0.f, 0.f};

  for (int k0 = 0; k0 < K; k0 += 64) {
    short8 va[4], vb[4];
#pragma unroll
    for (int it = 0; it < 4; ++it) {
      int idx = it * 256 + tid;
      int row = idx >> 3;   // 8 chunks of 8 elems per row
      int c = idx & 7;
      const f32x4* ap = (const f32x4*)(A + (mBase + row) * K + k0 + c * 8);
      const f32x4* wp = (const f32x4*)(W + (nBase + row) * K + k0 + c * 8);
      va[it] = cvt8(ap[0], ap[1]);
      vb[it] = cvt8(wp[0], wp[1]);
    }
    __syncthreads();
#pragma unroll
    for (int it = 0; it < 4; ++it) {
      int idx = it * 256 + tid;
      int row = idx >> 3;
      int c = idx & 7;
      *(short8*)(As + row * GST + c * 8) = va[it];
      *(short8*)(Bs + row * GST + c * 8) = vb[it];
    }
    __syncthreads();
#pragma unroll
    for (int ks = 0; ks < 2; ++ks) {
      short8 af[4], bfr[4];
#pragma unroll
      for (int t = 0; t < 4; ++t) {
        int rowA = wm * 64 + t * 16 + col;
        int rowB = wn * 64 + t * 16 + col;
        int kc = ks * 4 + quad;
        af[t] = *(const short8*)(As + rowA * GST + kc * 8);
        bfr[t] = *(const short8*)(Bs + rowB * GST + kc * 8);
      }
#pragma unroll
      for (int i = 0; i < 4; ++i)
#pragma unroll
        for (int j = 0; j < 4; ++j)
          acc[i][j] = __builtin_amdgcn_mfma_f32_16x16x32_bf16(af[i], bfr[j], acc[i][j], 0, 0, 0);
    }
  }
#pragma unroll
  for (int j = 0; j < 4; ++j) {
    long n = nBase + wn * 64 + j * 16 + col;
    float bv = bias[n];
#pragma unroll
    for (int i = 0; i < 4; ++i) {
      long m0 = mBase + wm * 64 + i * 16 + quad * 4;
#pragma unroll
      for (int r = 0; r < 4; ++r)
        C[(m0 + r) * N + n] = (bf16)(acc[i][j][r] + bv);
    }
  }
}

// ---------------- mask dtype probe ----------------
// flags[0]: int32-{0,1} violations; flags[1]: u16-{0,1,bf16/fp16 one} violations;
// flags[2]: fp32-{0,1.0f} violations. All reads stay within 32 KB (min layout).
__global__ void probe_mask_kernel(const void* maskp, float* flags) {
  int i = blockIdx.x * 256 + threadIdx.x;  // 16384 threads
  const unsigned short* mh = (const unsigned short*)maskp;
  unsigned short hv = mh[i];
  if (hv != 0 && hv != 1 && hv != 0x3F80 && hv != 0x3C00)
    atomicAdd(&flags[1], 1.0f);
  if (i < 8192) {
    unsigned int v = ((const unsigned int*)maskp)[i];
    if (v != 0u && v != 1u) atomicAdd(&flags[0], 1.0f);
    if (v != 0u && v != 0x3F800000u) atomicAdd(&flags[2], 1.0f);
  }
}

// ---------------- naive (VALU, obviously-correct) attention ----------------
// One wave per (b,h,q). Writes ctx in place into Q slot of qkv; accumulates
// colsum[b,k] = sum_{h,q} softmax_w[b,h,q,k] via LDS block partials + atomics.
__global__ __launch_bounds__(256, 2) void attn_naive(
    bf16* __restrict__ qkv, const void* __restrict__ maskp,
    const float* __restrict__ flags, float* __restrict__ colsum)
{
  __shared__ float s_sh[4][NS];   // 32 KB
  __shared__ float q_sh[4][NDH];  // 4 KB
  __shared__ float cs_blk[NS];    // 8 KB
  const int tid = threadIdx.x, wave = tid >> 6, lane = tid & 63;
  const int b = blockIdx.z, h = blockIdx.y;
  const int q = blockIdx.x * 4 + wave;
  bf16* base = qkv + (long)b * NS * (3 * NE);
  bf16* Qg = base + h * NDH;
  const bf16* Kg = base + NE + h * NDH;
  const bf16* Vg = base + 2 * NE + h * NDH;

  for (int i = tid; i < NS; i += 256) cs_blk[i] = 0.f;
  for (int d = lane; d < NDH; d += 64)
    q_sh[wave][d] = (float)Qg[(long)q * (3 * NE) + d];
  __syncthreads();

  int mmode;
  if (flags[0] == 0.f) mmode = 0;        // int32 {0,1}
  else if (flags[2] == 0.f) mmode = 3;   // fp32 {0,1.0}
  else if (flags[1] == 0.f) mmode = 1;   // 16-bit
  else mmode = 2;                        // bytes
  const int* mi = (const int*)maskp;
  const unsigned int* mu = (const unsigned int*)maskp;
  const unsigned short* mh = (const unsigned short*)maskp;
  const unsigned char* mc = (const unsigned char*)maskp;

  const float scale = 0.0625f;  // 1/sqrt(256)
  float mrun = -3e38f;
  // score pass: lanes over k (k = kb + lane), serial over d
  for (int kb = 0; kb < NS; kb += 64) {
    int k = kb + lane;
    const bf16* Kr = Kg + (long)k * (3 * NE);
    float a0 = 0.f, a1 = 0.f, a2 = 0.f, a3 = 0.f;
    for (int dc = 0; dc < NDH; dc += 8) {
      short8 kv = *(const short8*)(Kr + dc);
      a0 += q_sh[wave][dc + 0] * b2f(kv[0]);
      a1 += q_sh[wave][dc + 1] * b2f(kv[1]);
      a2 += q_sh[wave][dc + 2] * b2f(kv[2]);
      a3 += q_sh[wave][dc + 3] * b2f(kv[3]);
      a0 += q_sh[wave][dc + 4] * b2f(kv[4]);
      a1 += q_sh[wave][dc + 5] * b2f(kv[5]);
      a2 += q_sh[wave][dc + 6] * b2f(kv[6]);
      a3 += q_sh[wave][dc + 7] * b2f(kv[7]);
    }
    int midx = b * NS + k;
    bool valid = (mmode == 0) ? (mi[midx] != 0)
               : (mmode == 3) ? (mu[midx] != 0u)
               : (mmode == 1) ? (mh[midx] != 0)
                              : (mc[midx] != 0);
    float s = valid ? (a0 + a1 + a2 + a3) * scale : -1e9f;
    s_sh[wave][k] = s;
    mrun = fmaxf(mrun, s);
  }
#pragma unroll
  for (int off = 1; off < 64; off <<= 1) mrun = fmaxf(mrun, __shfl_xor(mrun, off));
  // l + convert scores to unnormalized p in LDS
  float l = 0.f;
  for (int k = lane; k < NS; k += 64) {
    float p = __expf(s_sh[wave][k] - mrun);
    s_sh[wave][k] = p;
    l += p;
  }
#pragma unroll
  for (int off = 1; off < 64; off <<= 1) l += __shfl_xor(l, off);
  const float invl = 1.0f / l;

  // PV: serial over k, lanes over d (4 contiguous d per lane)
  float o0 = 0.f, o1 = 0.f, o2 = 0.f, o3 = 0.f;
  for (int k = 0; k < NS; ++k) {
    float p = s_sh[wave][k];  // LDS broadcast
    s16x4 vv = *(const s16x4*)(Vg + (long)k * (3 * NE) + lane * 4);
    o0 += p * b2f(vv[0]);
    o1 += p * b2f(vv[1]);
    o2 += p * b2f(vv[2]);
    o3 += p * b2f(vv[3]);
  }
  // colsum partials into block-shared LDS
  for (int k = lane; k < NS; k += 64) atomicAdd(&cs_blk[k], s_sh[wave][k] * invl);
  // write ctx in place into the Q slot (own row, own head columns only)
  {
    bf16* Cr = Qg + (long)q * (3 * NE) + lane * 4;
    Cr[0] = (bf16)(o0 * invl);
    Cr[1] = (bf16)(o1 * invl);
    Cr[2] = (bf16)(o2 * invl);
    Cr[3] = (bf16)(o3 * invl);
  }
  __syncthreads();
  for (int k = tid; k < NS; k += 256) atomicAdd(&colsum[b * NS + k], cs_blk[k]);
}

// ---------------- tails ----------------
__global__ void zero_ws_kernel(float* __restrict__ colsum, float* __restrict__ g,
                               float* __restrict__ flags) {
  int i = blockIdx.x * 256 + threadIdx.x;
  if (i < NB * NS) colsum[i] = 0.f;
  if (i < NB * NE) g[i] = 0.f;
  if (i < 16) flags[i] = 0.f;
}

// g[b,f] += sum_{s in chunk} colsum[b,s] * ctx[b,s,f]  (ctx in Q region, stride 3E)
__global__ void weighted_ctx_kernel(const float* __restrict__ colsum,
                                    const bf16* __restrict__ qkv,
                                    float* __restrict__ g) {
  int b = blockIdx.y;
  int f = blockIdx.x * 256 + threadIdx.x;
  int s0 = blockIdx.z * 256;
  float acc = 0.f;
  for (int s = s0; s < s0 + 256; ++s)
    acc += colsum[b * NS + s] * (float)qkv[((long)(b * NS + s)) * (3 * NE) + f];
  atomicAdd(&g[b * NE + f], acc);
}

// out[b,e] = (1/H) * sum_f g[b,f]*Wout[e,f] + S * bout[e]
// (sum_k colsum[b,k] == H*S exactly: softmax rows sum to 1)
__global__ void final_gemv_kernel(const float* __restrict__ g,
                                  const float* __restrict__ w_out,
                                  const float* __restrict__ b_out,
                                  float* __restrict__ out) {
  __shared__ float gs[NE];
  int b = blockIdx.y;
  int e = blockIdx.x * 256 + threadIdx.x;
  for (int i = threadIdx.x; i < NE; i += 256) gs[i] = g[b * NE + i];
  __syncthreads();
  float acc = 0.f;
  for (int f = 0; f < NE; f += 4) {
    f32x4 w = *(const f32x4*)(w_out + (long)e * NE + f);
    acc += gs[f + 0] * w[0] + gs[f + 1] * w[1] + gs[f + 2] * w[2] + gs[f + 3] * w[3];
  }
  out[b * NE + e] = acc * (1.0f / NH) + (float)NS * b_out[e];
}

__global__ void sentinel_kernel(float* __restrict__ out, float v) {
  int i = blockIdx.x * 256 + threadIdx.x;
  if (i < NB * NE) out[i] = v;
}

extern "C" void kernel_launch(void* const* d_in, const int* in_sizes, int n_in,
                              void* d_out, int out_size, void* d_ws, size_t ws_size,
                              hipStream_t stream) {
  const float* x     = (const float*)d_in[0];
  const void*  maskp = d_in[1];
  const float* w_in  = (const float*)d_in[2];
  const float* b_in  = (const float*)d_in[3];
  const float* w_out = (const float*)d_in[4];
  const float* b_out = (const float*)d_in[5];
  float* out = (float*)d_out;

  // --- host-side interface guards (encode diagnosis into finite absmax) ---
  bool ok_sizes = (n_in == 6) &&
                  in_sizes[0] == NB * NS * NE && in_sizes[1] == NB * NS &&
                  in_sizes[2] == 3 * NE * NE && in_sizes[3] == 3 * NE &&
                  in_sizes[4] == NE * NE && in_sizes[5] == NE &&
                  out_size == NB * NE;
  if (!ok_sizes) {  // absmax ~676 => input layout mismatch
    sentinel_kernel<<<dim3(64), dim3(256), 0, stream>>>(out, 222.0f);
    return;
  }
  const size_t NEED = 201326592ULL /*qkv bf16*/ + 131072ULL /*colsum*/ +
                      65536ULL /*g*/ + 64ULL /*flags*/;
  if (ws_size < NEED) {  // absmax ~565 => workspace too small
    sentinel_kernel<<<dim3(64), dim3(256), 0, stream>>>(out, 111.0f);
    return;
  }

  char* ws = (char*)d_ws;
  bf16* qkv     = (bf16*)ws;                   // 201,326,592 B
  float* colsum = (float*)(ws + 201326592);    // 131,072 B
  float* g      = (float*)(ws + 201457664);    // 65,536 B
  float* flags  = (float*)(ws + 201523200);    // 64 B

  zero_ws_kernel<<<dim3(128), dim3(256), 0, stream>>>(colsum, g, flags);
  probe_mask_kernel<<<dim3(64), dim3(256), 0, stream>>>(maskp, flags);
  gemm_bt_bias<<<dim3(256, 24), dim3(256), 0, stream>>>(x, w_in, b_in, qkv,
                                                        NB * NS, 3 * NE, NE);
  attn_naive<<<dim3(NS / 4, NH, NB), dim3(256), 0, stream>>>(qkv, maskp, flags, colsum);
  weighted_ctx_kernel<<<dim3(NE / 256, NB, NS / 256), dim3(256), 0, stream>>>(colsum, qkv, g);
  final_gemv_kernel<<<dim3(NE / 256, NB), dim3(256), 0, stream>>>(g, w_out, b_out, out);
}

// Round 7
// 5923.514 us; speedup vs baseline: 7.2745x; 7.2745x over previous
//
#include <hip/hip_runtime.h>
#include <hip/hip_bf16.h>

#define NB 16
#define NS 2048
#define NE 1024
#define NH 4
#define NDH 256

typedef __hip_bfloat16 bf16;
typedef __attribute__((ext_vector_type(8))) short short8;
typedef __attribute__((ext_vector_type(4))) float f32x4;

__device__ __forceinline__ short f2b(float f) {
  bf16 h = (bf16)f;
  return *(short*)&h;
}

__device__ __forceinline__ short8 cvt8(f32x4 a, f32x4 b) {
  short8 r;
  r[0] = f2b(a[0]); r[1] = f2b(a[1]); r[2] = f2b(a[2]); r[3] = f2b(a[3]);
  r[4] = f2b(b[0]); r[5] = f2b(b[1]); r[6] = f2b(b[2]); r[7] = f2b(b[3]);
  return r;
}

// ---- GEMM1: qkv(bf16) = x(fp32) @ W(fp32)^T + b(fp32) ----
#define GST 72
__global__ __launch_bounds__(256, 1) void gemm_bt_bias(
    const float* __restrict__ A, const float* __restrict__ W,
    const float* __restrict__ bias, bf16* __restrict__ C,
    int M, int N, int K)
{
  __shared__ __attribute__((aligned(16))) bf16 As[128 * GST];
  __shared__ __attribute__((aligned(16))) bf16 Bs[128 * GST];
  const int tid = threadIdx.x;
  const int wave = tid >> 6;
  const int lane = tid & 63;
  const int quad = lane >> 4;
  const int col = lane & 15;
  const int wm = wave & 1, wn = wave >> 1;
  const long mBase = (long)blockIdx.x * 128;
  const long nBase = (long)blockIdx.y * 128;

  f32x4 acc[4][4];
#pragma unroll
  for (int i = 0; i < 4; ++i)
#pragma unroll
    for (int j = 0; j < 4; ++j) acc[i][j] = (f32x4){0.f, 0.f, 0.f, 0.f};

  for (int k0 = 0; k0 < K; k0 += 64) {
    short8 va[4], vb[4];
#pragma unroll
    for (int it = 0; it < 4; ++it) {
      int idx = it * 256 + tid;
      int row = idx >> 3;
      int c = idx & 7;
      const f32x4* ap = (const f32x4*)(A + (mBase + row) * K + k0 + c * 8);
      const f32x4* wp = (const f32x4*)(W + (nBase + row) * K + k0 + c * 8);
      va[it] = cvt8(ap[0], ap[1]);
      vb[it] = cvt8(wp[0], wp[1]);
    }
    __syncthreads();
#pragma unroll
    for (int it = 0; it < 4; ++it) {
      int idx = it * 256 + tid;
      int row = idx >> 3;
      int c = idx & 7;
      *(short8*)(As + row * GST + c * 8) = va[it];
      *(short8*)(Bs + row * GST + c * 8) = vb[it];
    }
    __syncthreads();
#pragma unroll
    for (int ks = 0; ks < 2; ++ks) {
      short8 af[4], bfr[4];
#pragma unroll
      for (int t = 0; t < 4; ++t) {
        int rowA = wm * 64 + t * 16 + col;
        int rowB = wn * 64 + t * 16 + col;
        int kc = ks * 4 + quad;
        af[t] = *(const short8*)(As + rowA * GST + kc * 8);
        bfr[t] = *(const short8*)(Bs + rowB * GST + kc * 8);
      }
#pragma unroll
      for (int i = 0; i < 4; ++i)
#pragma unroll
        for (int j = 0; j < 4; ++j)
          acc[i][j] = __builtin_amdgcn_mfma_f32_16x16x32_bf16(af[i], bfr[j], acc[i][j], 0, 0, 0);
    }
  }
#pragma unroll
  for (int j = 0; j < 4; ++j) {
    long n = nBase + wn * 64 + j * 16 + col;
    float bv = bias[n];
#pragma unroll
    for (int i = 0; i < 4; ++i) {
      long m0 = mBase + wm * 64 + i * 16 + quad * 4;
#pragma unroll
      for (int r = 0; r < 4; ++r)
        C[(m0 + r) * N + n] = (bf16)(acc[i][j][r] + bv);
    }
  }
}

// ---------------- mask dtype probe (validated green in R6) ----------------
__global__ void probe_mask_kernel(const void* maskp, float* flags) {
  int i = blockIdx.x * 256 + threadIdx.x;  // 16384 threads
  const unsigned short* mh = (const unsigned short*)maskp;
  unsigned short hv = mh[i];
  if (hv != 0 && hv != 1 && hv != 0x3F80 && hv != 0x3C00)
    atomicAdd(&flags[1], 1.0f);
  if (i < 8192) {
    unsigned int v = ((const unsigned int*)maskp)[i];
    if (v != 0u && v != 1u) atomicAdd(&flags[0], 1.0f);
    if (v != 0u && v != 0x3F800000u) atomicAdd(&flags[2], 1.0f);
  }
}

// maskf[b,k] = valid ? 0 : -1e9  (additive score bias)
__global__ void prep_mask_kernel(const void* maskp, const float* __restrict__ flags,
                                 float* __restrict__ maskf) {
  int i = blockIdx.x * 256 + threadIdx.x;
  if (i >= NB * NS) return;
  int mmode;
  if (flags[0] == 0.f) mmode = 0;
  else if (flags[2] == 0.f) mmode = 3;
  else if (flags[1] == 0.f) mmode = 1;
  else mmode = 2;
  bool valid;
  if (mmode == 0) valid = ((const int*)maskp)[i] != 0;
  else if (mmode == 3) valid = ((const unsigned int*)maskp)[i] != 0u;
  else if (mmode == 1) valid = ((const unsigned short*)maskp)[i] != 0;
  else valid = ((const unsigned char*)maskp)[i] != 0;
  maskf[i] = valid ? 0.f : -1e9f;
}

// ---------------- MFMA two-pass flash attention ----------------
// 32 q-rows per block, per (b,h). ctx written in place into Q slot of qkv.
// colsum[b,k] += sum_{h,q} softmax_w via atomics.
#define QST 264
#define VST 40
__global__ __launch_bounds__(256, 2) void attn_kernel(
    bf16* __restrict__ qkv, const float* __restrict__ maskf,
    float* __restrict__ colsum)
{
  __shared__ __attribute__((aligned(16))) bf16 Qs[32 * QST];
  __shared__ __attribute__((aligned(16))) bf16 Ks[32 * QST];
  __shared__ __attribute__((aligned(16))) bf16 Vt[256 * VST];  // V^T tile
  __shared__ __attribute__((aligned(16))) bf16 Ps[32 * VST];
  __shared__ float m_run[32], l_run[32], inv_l[32];
  __shared__ float red[2][32];

  const int tid = threadIdx.x;
  const int wave = tid >> 6;
  const int lane = tid & 63;
  const int quad = lane >> 4;
  const int col = lane & 15;
  const int qt = wave & 1;     // q-subtile for QK phase
  const int ksub = wave >> 1;  // k-subtile for QK phase
  const int b = blockIdx.z, h = blockIdx.y;
  const int qBase = blockIdx.x * 32;

  bf16* Qg = qkv + (long)b * NS * (3 * NE) + h * NDH;
  const bf16* Kg = Qg + NE;
  const bf16* Vg = Qg + 2 * NE;

  // load Q tile [32][256]
#pragma unroll
  for (int it = 0; it < 4; ++it) {
    int idx = it * 256 + tid;
    int row = idx >> 5;
    int c = idx & 31;
    short8 v = *(const short8*)(Qg + (long)(qBase + row) * (3 * NE) + c * 8);
    *(short8*)(Qs + row * QST + c * 8) = v;
  }
  if (tid < 32) { m_run[tid] = -3e38f; l_run[tid] = 0.f; }
  __syncthreads();

  const float scale = 0.0625f;  // 1/sqrt(256)

  // ---------------- pass 1: m, l ----------------
  for (int kt = 0; kt < NS / 32; ++kt) {
#pragma unroll
    for (int it = 0; it < 4; ++it) {
      int idx = it * 256 + tid;
      int row = idx >> 5;
      int c = idx & 31;
      short8 v = *(const short8*)(Kg + (long)(kt * 32 + row) * (3 * NE) + c * 8);
      *(short8*)(Ks + row * QST + c * 8) = v;
    }
    __syncthreads();
    f32x4 s = (f32x4){0.f, 0.f, 0.f, 0.f};
    {
      int rowA = qt * 16 + col;
      int rowB = ksub * 16 + col;
#pragma unroll
      for (int ks = 0; ks < 8; ++ks) {
        int kc = ks * 4 + quad;
        short8 a = *(const short8*)(Qs + rowA * QST + kc * 8);
        short8 kb = *(const short8*)(Ks + rowB * QST + kc * 8);
        s = __builtin_amdgcn_mfma_f32_16x16x32_bf16(a, kb, s, 0, 0, 0);
      }
    }
    float mbias = maskf[b * NS + kt * 32 + ksub * 16 + col];
    f32x4 sv;
#pragma unroll
    for (int r = 0; r < 4; ++r) sv[r] = s[r] * scale + mbias;
    f32x4 rm = sv;
#pragma unroll
    for (int off = 1; off < 16; off <<= 1) {
#pragma unroll
      for (int r = 0; r < 4; ++r) rm[r] = fmaxf(rm[r], __shfl_xor(rm[r], off));
    }
    if (col == 0) {
#pragma unroll
      for (int r = 0; r < 4; ++r) red[ksub][qt * 16 + quad * 4 + r] = rm[r];
    }
    __syncthreads();
    if (tid < 32) {
      float mt = fmaxf(red[0][tid], red[1][tid]);
      float mn = fmaxf(m_run[tid], mt);
      l_run[tid] *= __expf(m_run[tid] - mn);
      m_run[tid] = mn;
    }
    __syncthreads();
    f32x4 es;
#pragma unroll
    for (int r = 0; r < 4; ++r)
      es[r] = __expf(sv[r] - m_run[qt * 16 + quad * 4 + r]);
#pragma unroll
    for (int off = 1; off < 16; off <<= 1) {
#pragma unroll
      for (int r = 0; r < 4; ++r) es[r] += __shfl_xor(es[r], off);
    }
    if (col == 0) {
#pragma unroll
      for (int r = 0; r < 4; ++r) red[ksub][qt * 16 + quad * 4 + r] = es[r];
    }
    __syncthreads();
    if (tid < 32) l_run[tid] += red[0][tid] + red[1][tid];
    __syncthreads();
  }

  if (tid < 32) inv_l[tid] = 1.0f / l_run[tid];
  __syncthreads();

  // ---------------- pass 2: P, colsum, PV ----------------
  f32x4 acc[2][4];
#pragma unroll
  for (int i = 0; i < 2; ++i)
#pragma unroll
    for (int j = 0; j < 4; ++j) acc[i][j] = (f32x4){0.f, 0.f, 0.f, 0.f};

  for (int kt = 0; kt < NS / 32; ++kt) {
#pragma unroll
    for (int it = 0; it < 4; ++it) {
      int idx = it * 256 + tid;
      int row = idx >> 5;
      int c = idx & 31;
      short8 v = *(const short8*)(Kg + (long)(kt * 32 + row) * (3 * NE) + c * 8);
      *(short8*)(Ks + row * QST + c * 8) = v;
    }
    // V tile transposed through VGPRs: Vt[d][kk] = V[kt*32+kk][d]
#pragma unroll
    for (int it = 0; it < 4; ++it) {
      int idx = it * 256 + tid;
      int kk = idx >> 5;
      int dc = idx & 31;
      short8 v = *(const short8*)(Vg + (long)(kt * 32 + kk) * (3 * NE) + dc * 8);
#pragma unroll
      for (int j = 0; j < 8; ++j)
        ((short*)Vt)[(dc * 8 + j) * VST + kk] = v[j];
    }
    __syncthreads();
    f32x4 s = (f32x4){0.f, 0.f, 0.f, 0.f};
    {
      int rowA = qt * 16 + col;
      int rowB = ksub * 16 + col;
#pragma unroll
      for (int ks = 0; ks < 8; ++ks) {
        int kc = ks * 4 + quad;
        short8 a = *(const short8*)(Qs + rowA * QST + kc * 8);
        short8 kb = *(const short8*)(Ks + rowB * QST + kc * 8);
        s = __builtin_amdgcn_mfma_f32_16x16x32_bf16(a, kb, s, 0, 0, 0);
      }
    }
    float mbias = maskf[b * NS + kt * 32 + ksub * 16 + col];
    float cs = 0.f;
#pragma unroll
    for (int r = 0; r < 4; ++r) {
      int q = qt * 16 + quad * 4 + r;
      float svr = s[r] * scale + mbias;
      float p = __expf(svr - m_run[q]);  // in [0,1]
      cs += p * inv_l[q];
      int kk = ksub * 16 + col;
      Ps[q * VST + kk] = (bf16)p;
    }
    cs += __shfl_xor(cs, 16);
    cs += __shfl_xor(cs, 32);
    if (lane < 16)
      atomicAdd(&colsum[b * NS + kt * 32 + ksub * 16 + lane], cs);
    __syncthreads();
    // PV: ctx[q][d] += P[q][kk] * V[kk][d]
    short8 pa[2];
#pragma unroll
    for (int q2 = 0; q2 < 2; ++q2) {
      int q = q2 * 16 + col;
      pa[q2] = *(const short8*)(Ps + q * VST + quad * 8);
    }
#pragma unroll
    for (int dt = 0; dt < 4; ++dt) {
      int d = wave * 64 + dt * 16 + col;
      short8 vb = *(const short8*)(Vt + d * VST + quad * 8);
#pragma unroll
      for (int q2 = 0; q2 < 2; ++q2)
        acc[q2][dt] = __builtin_amdgcn_mfma_f32_16x16x32_bf16(pa[q2], vb, acc[q2][dt], 0, 0, 0);
    }
    __syncthreads();
  }

  // epilogue: ctx in place into the Q slot (row stride 3E)
#pragma unroll
  for (int q2 = 0; q2 < 2; ++q2)
#pragma unroll
    for (int dt = 0; dt < 4; ++dt)
#pragma unroll
      for (int r = 0; r < 4; ++r) {
        int q = q2 * 16 + quad * 4 + r;
        int d = wave * 64 + dt * 16 + col;
        Qg[(long)(qBase + q) * (3 * NE) + d] = (bf16)(acc[q2][dt][r] * inv_l[q]);
      }
}

// ---------------- tails ----------------
__global__ void zero_ws_kernel(float* __restrict__ colsum, float* __restrict__ g,
                               float* __restrict__ flags) {
  int i = blockIdx.x * 256 + threadIdx.x;
  if (i < NB * NS) colsum[i] = 0.f;
  if (i < NB * NE) g[i] = 0.f;
  if (i < 16) flags[i] = 0.f;
}

__global__ void weighted_ctx_kernel(const float* __restrict__ colsum,
                                    const bf16* __restrict__ qkv,
                                    float* __restrict__ g) {
  int b = blockIdx.y;
  int f = blockIdx.x * 256 + threadIdx.x;
  int s0 = blockIdx.z * 256;
  float acc = 0.f;
  for (int s = s0; s < s0 + 256; ++s)
    acc += colsum[b * NS + s] * (float)qkv[((long)(b * NS + s)) * (3 * NE) + f];
  atomicAdd(&g[b * NE + f], acc);
}

// out[b,e] = (1/H) * sum_f g[b,f]*Wout[e,f] + S * bout[e]
__global__ void final_gemv_kernel(const float* __restrict__ g,
                                  const float* __restrict__ w_out,
                                  const float* __restrict__ b_out,
                                  float* __restrict__ out) {
  __shared__ float gs[NE];
  int b = blockIdx.y;
  int e = blockIdx.x * 256 + threadIdx.x;
  for (int i = threadIdx.x; i < NE; i += 256) gs[i] = g[b * NE + i];
  __syncthreads();
  float acc = 0.f;
  for (int f = 0; f < NE; f += 4) {
    f32x4 w = *(const f32x4*)(w_out + (long)e * NE + f);
    acc += gs[f + 0] * w[0] + gs[f + 1] * w[1] + gs[f + 2] * w[2] + gs[f + 3] * w[3];
  }
  out[b * NE + e] = acc * (1.0f / NH) + (float)NS * b_out[e];
}

__global__ void sentinel_kernel(float* __restrict__ out, float v) {
  int i = blockIdx.x * 256 + threadIdx.x;
  if (i < NB * NE) out[i] = v;
}

extern "C" void kernel_launch(void* const* d_in, const int* in_sizes, int n_in,
                              void* d_out, int out_size, void* d_ws, size_t ws_size,
                              hipStream_t stream) {
  const float* x     = (const float*)d_in[0];
  const void*  maskp = d_in[1];
  const float* w_in  = (const float*)d_in[2];
  const float* b_in  = (const float*)d_in[3];
  const float* w_out = (const float*)d_in[4];
  const float* b_out = (const float*)d_in[5];
  float* out = (float*)d_out;

  bool ok_sizes = (n_in == 6) &&
                  in_sizes[0] == NB * NS * NE && in_sizes[1] == NB * NS &&
                  in_sizes[2] == 3 * NE * NE && in_sizes[3] == 3 * NE &&
                  in_sizes[4] == NE * NE && in_sizes[5] == NE &&
                  out_size == NB * NE;
  if (!ok_sizes) {
    sentinel_kernel<<<dim3(64), dim3(256), 0, stream>>>(out, 222.0f);
    return;
  }
  const size_t NEED = 201326592ULL + 131072ULL + 65536ULL + 64ULL + 131072ULL;
  if (ws_size < NEED) {
    sentinel_kernel<<<dim3(64), dim3(256), 0, stream>>>(out, 111.0f);
    return;
  }

  char* ws = (char*)d_ws;
  bf16* qkv     = (bf16*)ws;                   // 201,326,592 B
  float* colsum = (float*)(ws + 201326592);    // 131,072 B
  float* g      = (float*)(ws + 201457664);    // 65,536 B
  float* flags  = (float*)(ws + 201523200);    // 64 B
  float* maskf  = (float*)(ws + 201523264);    // 131,072 B

  zero_ws_kernel<<<dim3(128), dim3(256), 0, stream>>>(colsum, g, flags);
  probe_mask_kernel<<<dim3(64), dim3(256), 0, stream>>>(maskp, flags);
  prep_mask_kernel<<<dim3(128), dim3(256), 0, stream>>>(maskp, flags, maskf);
  gemm_bt_bias<<<dim3(256, 24), dim3(256), 0, stream>>>(x, w_in, b_in, qkv,
                                                        NB * NS, 3 * NE, NE);
  attn_kernel<<<dim3(NS / 32, NH, NB), dim3(256), 0, stream>>>(qkv, maskf, colsum);
  weighted_ctx_kernel<<<dim3(NE / 256, NB, NS / 256), dim3(256), 0, stream>>>(colsum, qkv, g);
  final_gemv_kernel<<<dim3(NE / 256, NB), dim3(256), 0, stream>>>(g, w_out, b_out, out);
}

// Round 8
// 2327.738 us; speedup vs baseline: 18.5118x; 2.5448x over previous
//
#include <hip/hip_runtime.h>
#include <hip/hip_bf16.h>

#define NB 16
#define NS 2048
#define NE 1024
#define NH 4
#define NDH 256

typedef __hip_bfloat16 bf16;
typedef __attribute__((ext_vector_type(8))) short short8;
typedef __attribute__((ext_vector_type(4))) float f32x4;

__device__ __forceinline__ short f2b(float f) {
  bf16 h = (bf16)f;
  return *(short*)&h;
}

__device__ __forceinline__ short8 cvt8(f32x4 a, f32x4 b) {
  short8 r;
  r[0] = f2b(a[0]); r[1] = f2b(a[1]); r[2] = f2b(a[2]); r[3] = f2b(a[3]);
  r[4] = f2b(b[0]); r[5] = f2b(b[1]); r[6] = f2b(b[2]); r[7] = f2b(b[3]);
  return r;
}

// ---- GEMM1: Q,K planar + V transposed (Vtg[b,h,d,s]) from x(fp32)@W^T+b ----
#define GST 72
__global__ __launch_bounds__(256, 1) void gemm_qkvt(
    const float* __restrict__ A, const float* __restrict__ W,
    const float* __restrict__ bias, bf16* __restrict__ Qb,
    bf16* __restrict__ Kb, bf16* __restrict__ Vtg)
{
  __shared__ __attribute__((aligned(16))) char smem[36864];
  bf16* As = (bf16*)smem;
  bf16* Bs = As + 128 * GST;
  const int tid = threadIdx.x;
  const int wave = tid >> 6;
  const int lane = tid & 63;
  const int quad = lane >> 4;
  const int col = lane & 15;
  const int wm = wave & 1, wn = wave >> 1;
  const long mBase = (long)blockIdx.x * 128;
  const long nBase = (long)blockIdx.y * 128;
  const int K = NE;

  f32x4 acc[4][4];
#pragma unroll
  for (int i = 0; i < 4; ++i)
#pragma unroll
    for (int j = 0; j < 4; ++j) acc[i][j] = (f32x4){0.f, 0.f, 0.f, 0.f};

  for (int k0 = 0; k0 < K; k0 += 64) {
    short8 va[4], vb[4];
#pragma unroll
    for (int it = 0; it < 4; ++it) {
      int idx = it * 256 + tid;
      int row = idx >> 3;
      int c = idx & 7;
      const f32x4* ap = (const f32x4*)(A + (mBase + row) * K + k0 + c * 8);
      const f32x4* wp = (const f32x4*)(W + (nBase + row) * K + k0 + c * 8);
      va[it] = cvt8(ap[0], ap[1]);
      vb[it] = cvt8(wp[0], wp[1]);
    }
    __syncthreads();
#pragma unroll
    for (int it = 0; it < 4; ++it) {
      int idx = it * 256 + tid;
      int row = idx >> 3;
      int c = idx & 7;
      *(short8*)(As + row * GST + c * 8) = va[it];
      *(short8*)(Bs + row * GST + c * 8) = vb[it];
    }
    __syncthreads();
#pragma unroll
    for (int ks = 0; ks < 2; ++ks) {
      short8 af[4], bfr[4];
#pragma unroll
      for (int t = 0; t < 4; ++t) {
        int rowA = wm * 64 + t * 16 + col;
        int rowB = wn * 64 + t * 16 + col;
        int kc = ks * 4 + quad;
        af[t] = *(const short8*)(As + rowA * GST + kc * 8);
        bfr[t] = *(const short8*)(Bs + rowB * GST + kc * 8);
      }
#pragma unroll
      for (int i = 0; i < 4; ++i)
#pragma unroll
        for (int j = 0; j < 4; ++j)
          acc[i][j] = __builtin_amdgcn_mfma_f32_16x16x32_bf16(af[i], bfr[j], acc[i][j], 0, 0, 0);
    }
  }

  if (nBase >= 2 * NE) {
    // V tile: bounce through LDS, write transposed rows coalesced.
    __syncthreads();  // As/Bs reads done before aliasing as T
    bf16* T = (bf16*)smem;  // [128][136]
#pragma unroll
    for (int j = 0; j < 4; ++j) {
      int n = wn * 64 + j * 16 + col;
      float bv = bias[nBase + n];
#pragma unroll
      for (int i = 0; i < 4; ++i) {
        int m = wm * 64 + i * 16 + quad * 4;
#pragma unroll
        for (int r = 0; r < 4; ++r)
          T[n * 136 + m + r] = (bf16)(acc[i][j][r] + bv);
      }
    }
    __syncthreads();
    long b = mBase >> 11;       // S = 2048
    long sOff = mBase & 2047;
    int v0 = (int)(nBase - 2 * NE);
#pragma unroll
    for (int t = 0; t < 8; ++t) {
      int idx = t * 256 + tid;
      int n = idx >> 4;
      int mc = idx & 15;
      short8 v = *(const short8*)(T + n * 136 + mc * 8);
      int g = v0 + n;
      int h = g >> 8, d = g & 255;
      *(short8*)(Vtg + ((b * NH + h) * NDH + d) * (long)NS + sOff + mc * 8) = v;
    }
  } else {
    bf16* dst = (nBase < NE) ? Qb : Kb;
    long nOff = (nBase < NE) ? nBase : nBase - NE;
#pragma unroll
    for (int j = 0; j < 4; ++j) {
      int nl = wn * 64 + j * 16 + col;
      float bv = bias[nBase + nl];
      long n = nOff + nl;
#pragma unroll
      for (int i = 0; i < 4; ++i) {
        long m0 = mBase + wm * 64 + i * 16 + quad * 4;
#pragma unroll
        for (int r = 0; r < 4; ++r)
          dst[(m0 + r) * NE + n] = (bf16)(acc[i][j][r] + bv);
      }
    }
  }
}

// ---------------- mask dtype probe (validated green in R6) ----------------
__global__ void probe_mask_kernel(const void* maskp, float* flags) {
  int i = blockIdx.x * 256 + threadIdx.x;  // 16384 threads
  const unsigned short* mh = (const unsigned short*)maskp;
  unsigned short hv = mh[i];
  if (hv != 0 && hv != 1 && hv != 0x3F80 && hv != 0x3C00)
    atomicAdd(&flags[1], 1.0f);
  if (i < 8192) {
    unsigned int v = ((const unsigned int*)maskp)[i];
    if (v != 0u && v != 1u) atomicAdd(&flags[0], 1.0f);
    if (v != 0u && v != 0x3F800000u) atomicAdd(&flags[2], 1.0f);
  }
}

// maskf[b,k] = valid ? 0 : -1e9  (additive score bias)
__global__ void prep_mask_kernel(const void* maskp, const float* __restrict__ flags,
                                 float* __restrict__ maskf) {
  int i = blockIdx.x * 256 + threadIdx.x;
  if (i >= NB * NS) return;
  int mmode;
  if (flags[0] == 0.f) mmode = 0;
  else if (flags[2] == 0.f) mmode = 3;
  else if (flags[1] == 0.f) mmode = 1;
  else mmode = 2;
  bool valid;
  if (mmode == 0) valid = ((const int*)maskp)[i] != 0;
  else if (mmode == 3) valid = ((const unsigned int*)maskp)[i] != 0u;
  else if (mmode == 1) valid = ((const unsigned short*)maskp)[i] != 0;
  else valid = ((const unsigned char*)maskp)[i] != 0;
  maskf[i] = valid ? 0.f : -1e9f;
}

// ---------------- MFMA two-pass flash attention ----------------
// 32 q-rows per block, per (b,h). V read pre-transposed from Vtg (no in-kernel
// transpose). ctx written in place into Qb. Swizzled Vts/Ps: conflict-free.
#define QST 264
__global__ __launch_bounds__(256, 3) void attn_kernel(
    bf16* __restrict__ Qb, const bf16* __restrict__ Kb,
    const bf16* __restrict__ Vtg, const float* __restrict__ maskf,
    float* __restrict__ colsum)
{
  __shared__ __attribute__((aligned(16))) bf16 Qs[32 * QST];   // 16.5 KB
  __shared__ __attribute__((aligned(16))) bf16 Ks[32 * QST];   // 16.5 KB
  __shared__ __attribute__((aligned(16))) bf16 Vts[256 * 32];  // 16 KB
  __shared__ __attribute__((aligned(16))) bf16 Ps[32 * 32];    // 2 KB
  __shared__ float m_run[32], l_run[32], inv_l[32];
  __shared__ float red[2][32];

  const int tid = threadIdx.x;
  const int wave = tid >> 6;
  const int lane = tid & 63;
  const int quad = lane >> 4;
  const int col = lane & 15;
  const int qt = wave & 1;     // q-subtile for QK phase
  const int ksub = wave >> 1;  // k-subtile for QK phase
  const int b = blockIdx.z, h = blockIdx.y;
  const int qBase = blockIdx.x * 32;

  const long qkRow = (long)b * NS;                 // row base into Qb/Kb
  const long vBase = ((long)(b * NH + h)) * NDH * NS;

  // load Q tile [32][256]
#pragma unroll
  for (int it = 0; it < 4; ++it) {
    int idx = it * 256 + tid;
    int row = idx >> 5;
    int c = idx & 31;
    short8 v = *(const short8*)(Qb + (qkRow + qBase + row) * NE + h * NDH + c * 8);
    *(short8*)(Qs + row * QST + c * 8) = v;
  }
  if (tid < 32) { m_run[tid] = -3e38f; l_run[tid] = 0.f; }
  __syncthreads();

  const float scale = 0.0625f;  // 1/sqrt(256)

  // ---------------- pass 1: m, l ----------------
  for (int kt = 0; kt < NS / 32; ++kt) {
#pragma unroll
    for (int it = 0; it < 4; ++it) {
      int idx = it * 256 + tid;
      int row = idx >> 5;
      int c = idx & 31;
      short8 v = *(const short8*)(Kb + (qkRow + kt * 32 + row) * NE + h * NDH + c * 8);
      *(short8*)(Ks + row * QST + c * 8) = v;
    }
    __syncthreads();
    f32x4 s = (f32x4){0.f, 0.f, 0.f, 0.f};
    {
      int rowA = qt * 16 + col;
      int rowB = ksub * 16 + col;
#pragma unroll
      for (int ks = 0; ks < 8; ++ks) {
        int kc = ks * 4 + quad;
        short8 a = *(const short8*)(Qs + rowA * QST + kc * 8);
        short8 kb = *(const short8*)(Ks + rowB * QST + kc * 8);
        s = __builtin_amdgcn_mfma_f32_16x16x32_bf16(a, kb, s, 0, 0, 0);
      }
    }
    float mbias = maskf[b * NS + kt * 32 + ksub * 16 + col];
    f32x4 sv;
#pragma unroll
    for (int r = 0; r < 4; ++r) sv[r] = s[r] * scale + mbias;
    f32x4 rm = sv;
#pragma unroll
    for (int off = 1; off < 16; off <<= 1) {
#pragma unroll
      for (int r = 0; r < 4; ++r) rm[r] = fmaxf(rm[r], __shfl_xor(rm[r], off));
    }
    if (col == 0) {
#pragma unroll
      for (int r = 0; r < 4; ++r) red[ksub][qt * 16 + quad * 4 + r] = rm[r];
    }
    __syncthreads();
    if (tid < 32) {
      float mt = fmaxf(red[0][tid], red[1][tid]);
      float mn = fmaxf(m_run[tid], mt);
      l_run[tid] *= __expf(m_run[tid] - mn);
      m_run[tid] = mn;
    }
    __syncthreads();
    f32x4 es;
#pragma unroll
    for (int r = 0; r < 4; ++r)
      es[r] = __expf(sv[r] - m_run[qt * 16 + quad * 4 + r]);
#pragma unroll
    for (int off = 1; off < 16; off <<= 1) {
#pragma unroll
      for (int r = 0; r < 4; ++r) es[r] += __shfl_xor(es[r], off);
    }
    if (col == 0) {
#pragma unroll
      for (int r = 0; r < 4; ++r) red[ksub][qt * 16 + quad * 4 + r] = es[r];
    }
    __syncthreads();
    if (tid < 32) l_run[tid] += red[0][tid] + red[1][tid];
    __syncthreads();
  }

  if (tid < 32) inv_l[tid] = 1.0f / l_run[tid];
  __syncthreads();

  // ---------------- pass 2: P, colsum, PV ----------------
  f32x4 acc[2][4];
#pragma unroll
  for (int i = 0; i < 2; ++i)
#pragma unroll
    for (int j = 0; j < 4; ++j) acc[i][j] = (f32x4){0.f, 0.f, 0.f, 0.f};

  for (int kt = 0; kt < NS / 32; ++kt) {
#pragma unroll
    for (int it = 0; it < 4; ++it) {
      int idx = it * 256 + tid;
      int row = idx >> 5;
      int c = idx & 31;
      short8 v = *(const short8*)(Kb + (qkRow + kt * 32 + row) * NE + h * NDH + c * 8);
      *(short8*)(Ks + row * QST + c * 8) = v;
    }
    // V^T tile: straight vector copy from Vtg, XOR chunk swizzle
#pragma unroll
    for (int it = 0; it < 4; ++it) {
      int idx = it * 256 + tid;
      int d = idx >> 2;
      int ch = idx & 3;
      short8 v = *(const short8*)(Vtg + vBase + (long)d * NS + kt * 32 + ch * 8);
      *(short8*)(Vts + d * 32 + ((ch ^ (d & 3)) << 3)) = v;
    }
    __syncthreads();
    f32x4 s = (f32x4){0.f, 0.f, 0.f, 0.f};
    {
      int rowA = qt * 16 + col;
      int rowB = ksub * 16 + col;
#pragma unroll
      for (int ks = 0; ks < 8; ++ks) {
        int kc = ks * 4 + quad;
        short8 a = *(const short8*)(Qs + rowA * QST + kc * 8);
        short8 kb = *(const short8*)(Ks + rowB * QST + kc * 8);
        s = __builtin_amdgcn_mfma_f32_16x16x32_bf16(a, kb, s, 0, 0, 0);
      }
    }
    int kk = ksub * 16 + col;
    float mbias = maskf[b * NS + kt * 32 + kk];
    float cs = 0.f;
#pragma unroll
    for (int r = 0; r < 4; ++r) {
      int q = qt * 16 + quad * 4 + r;
      float svr = s[r] * scale + mbias;
      float p = __expf(svr - m_run[q]);  // in [0,1]
      cs += p * inv_l[q];
      Ps[q * 32 + ((((kk >> 3) ^ ((q >> 2) & 3))) << 3) + (kk & 7)] = (bf16)p;
    }
    cs += __shfl_xor(cs, 16);
    cs += __shfl_xor(cs, 32);
    if (lane < 16)
      atomicAdd(&colsum[b * NS + kt * 32 + ksub * 16 + lane], cs);
    __syncthreads();
    // PV: ctx[q][d] += P[q][kk] * V^T[d][kk]
    short8 pa[2];
#pragma unroll
    for (int q2 = 0; q2 < 2; ++q2) {
      int q = q2 * 16 + col;
      pa[q2] = *(const short8*)(Ps + q * 32 + ((quad ^ ((q >> 2) & 3)) << 3));
    }
#pragma unroll
    for (int dt = 0; dt < 4; ++dt) {
      int d = wave * 64 + dt * 16 + col;
      short8 vb = *(const short8*)(Vts + d * 32 + ((quad ^ (d & 3)) << 3));
#pragma unroll
      for (int q2 = 0; q2 < 2; ++q2)
        acc[q2][dt] = __builtin_amdgcn_mfma_f32_16x16x32_bf16(pa[q2], vb, acc[q2][dt], 0, 0, 0);
    }
    __syncthreads();
  }

  // epilogue: ctx in place into Qb (sole reader of these rows was this block)
#pragma unroll
  for (int q2 = 0; q2 < 2; ++q2)
#pragma unroll
    for (int dt = 0; dt < 4; ++dt)
#pragma unroll
      for (int r = 0; r < 4; ++r) {
        int q = q2 * 16 + quad * 4 + r;
        int d = wave * 64 + dt * 16 + col;
        Qb[(qkRow + qBase + q) * NE + h * NDH + d] = (bf16)(acc[q2][dt][r] * inv_l[q]);
      }
}

// ---------------- tails ----------------
__global__ void zero_ws_kernel(float* __restrict__ colsum, float* __restrict__ g,
                               float* __restrict__ flags) {
  int i = blockIdx.x * 256 + threadIdx.x;
  if (i < NB * NS) colsum[i] = 0.f;
  if (i < NB * NE) g[i] = 0.f;
  if (i < 16) flags[i] = 0.f;
}

// g[b,f] += sum_{s in chunk} colsum[b,s] * ctx[b,s,f]  (ctx in Qb, stride E)
__global__ void weighted_ctx_kernel(const float* __restrict__ colsum,
                                    const bf16* __restrict__ Qb,
                                    float* __restrict__ g) {
  int b = blockIdx.y;
  int f = blockIdx.x * 256 + threadIdx.x;
  int s0 = blockIdx.z * 256;
  float acc = 0.f;
  for (int s = s0; s < s0 + 256; ++s)
    acc += colsum[b * NS + s] * (float)Qb[((long)(b * NS + s)) * NE + f];
  atomicAdd(&g[b * NE + f], acc);
}

// out[b,e] = (1/H) * sum_f g[b,f]*Wout[e,f] + S * bout[e]
__global__ void final_gemv_kernel(const float* __restrict__ g,
                                  const float* __restrict__ w_out,
                                  const float* __restrict__ b_out,
                                  float* __restrict__ out) {
  __shared__ float gs[NE];
  int b = blockIdx.y;
  int e = blockIdx.x * 256 + threadIdx.x;
  for (int i = threadIdx.x; i < NE; i += 256) gs[i] = g[b * NE + i];
  __syncthreads();
  float acc = 0.f;
  for (int f = 0; f < NE; f += 4) {
    f32x4 w = *(const f32x4*)(w_out + (long)e * NE + f);
    acc += gs[f + 0] * w[0] + gs[f + 1] * w[1] + gs[f + 2] * w[2] + gs[f + 3] * w[3];
  }
  out[b * NE + e] = acc * (1.0f / NH) + (float)NS * b_out[e];
}

__global__ void sentinel_kernel(float* __restrict__ out, float v) {
  int i = blockIdx.x * 256 + threadIdx.x;
  if (i < NB * NE) out[i] = v;
}

extern "C" void kernel_launch(void* const* d_in, const int* in_sizes, int n_in,
                              void* d_out, int out_size, void* d_ws, size_t ws_size,
                              hipStream_t stream) {
  const float* x     = (const float*)d_in[0];
  const void*  maskp = d_in[1];
  const float* w_in  = (const float*)d_in[2];
  const float* b_in  = (const float*)d_in[3];
  const float* w_out = (const float*)d_in[4];
  const float* b_out = (const float*)d_in[5];
  float* out = (float*)d_out;

  bool ok_sizes = (n_in == 6) &&
                  in_sizes[0] == NB * NS * NE && in_sizes[1] == NB * NS &&
                  in_sizes[2] == 3 * NE * NE && in_sizes[3] == 3 * NE &&
                  in_sizes[4] == NE * NE && in_sizes[5] == NE &&
                  out_size == NB * NE;
  if (!ok_sizes) {
    sentinel_kernel<<<dim3(64), dim3(256), 0, stream>>>(out, 222.0f);
    return;
  }
  const size_t NEED = 201326592ULL + 131072ULL + 65536ULL + 64ULL + 131072ULL;
  if (ws_size < NEED) {
    sentinel_kernel<<<dim3(64), dim3(256), 0, stream>>>(out, 111.0f);
    return;
  }

  char* ws = (char*)d_ws;
  bf16* Qb      = (bf16*)ws;                    // 67,108,864 B
  bf16* Kb      = (bf16*)(ws + 67108864);       // 67,108,864 B
  bf16* Vtg     = (bf16*)(ws + 134217728);      // 67,108,864 B  [B,H,DH,S]
  float* colsum = (float*)(ws + 201326592);     // 131,072 B
  float* g      = (float*)(ws + 201457664);     // 65,536 B
  float* flags  = (float*)(ws + 201523200);     // 64 B
  float* maskf  = (float*)(ws + 201523264);     // 131,072 B

  zero_ws_kernel<<<dim3(128), dim3(256), 0, stream>>>(colsum, g, flags);
  probe_mask_kernel<<<dim3(64), dim3(256), 0, stream>>>(maskp, flags);
  prep_mask_kernel<<<dim3(128), dim3(256), 0, stream>>>(maskp, flags, maskf);
  gemm_qkvt<<<dim3(256, 24), dim3(256), 0, stream>>>(x, w_in, b_in, Qb, Kb, Vtg);
  attn_kernel<<<dim3(NS / 32, NH, NB), dim3(256), 0, stream>>>(Qb, Kb, Vtg, maskf, colsum);
  weighted_ctx_kernel<<<dim3(NE / 256, NB, NS / 256), dim3(256), 0, stream>>>(colsum, Qb, g);
  final_gemv_kernel<<<dim3(NE / 256, NB), dim3(256), 0, stream>>>(g, w_out, b_out, out);
}